// Round 4
// baseline (66.555 us; speedup 1.0000x reference)
//
#include <hip/hip_runtime.h>
#include <hip/hip_fp16.h>

#define NN 1536      // n_nodes
#define FDIM 32      // p == fts == 32
#define TG 64        // GEMM tile: grid 24x24 = 576 blocks = 2.25/CU
#define KS 32        // K-step
#define NT (NN / KS) // 48 K-tiles

typedef __attribute__((ext_vector_type(8))) __bf16 bf16x8;
typedef __attribute__((ext_vector_type(4))) float f32x4;
typedef _Float16 h16x2 __attribute__((ext_vector_type(2)));

typedef __attribute__((address_space(3))) unsigned char as3_u8;
typedef __attribute__((address_space(1))) unsigned char as1_u8;

__device__ __forceinline__ void gload_lds16(const void* g, void* l) {
    __builtin_amdgcn_global_load_lds((const as1_u8*)g, (as3_u8*)l, 16, 0, 0);
}

// ---------------------------------------------------------------------------
// Split A into bf16 hi/lo: Ah = rne_bf16(a), Al = rne_bf16(a - float(Ah)).
// ---------------------------------------------------------------------------
__device__ __forceinline__ unsigned short bf16rne(float f) {
    unsigned u = __float_as_uint(f);
    return (unsigned short)((u + 0x7FFFu + ((u >> 16) & 1u)) >> 16);
}

__global__ __launch_bounds__(256) void gud_split(const float* __restrict__ A,
                                                 unsigned short* __restrict__ Ah,
                                                 unsigned short* __restrict__ Al) {
    int gid = blockIdx.x * 256 + threadIdx.x;      // 4 floats per thread
    float4 v = reinterpret_cast<const float4*>(A)[gid];
    ushort4 h, l;
    float x;
    x = v.x; h.x = bf16rne(x); l.x = bf16rne(x - __uint_as_float((unsigned)h.x << 16));
    x = v.y; h.y = bf16rne(x); l.y = bf16rne(x - __uint_as_float((unsigned)h.y << 16));
    x = v.z; h.z = bf16rne(x); l.z = bf16rne(x - __uint_as_float((unsigned)h.z << 16));
    x = v.w; h.w = bf16rne(x); l.w = bf16rne(x - __uint_as_float((unsigned)h.w << 16));
    reinterpret_cast<ushort4*>(Ah)[gid] = h;
    reinterpret_cast<ushort4*>(Al)[gid] = l;
}

// ---------------------------------------------------------------------------
// Prep: Q_l = P @ W1[l] for l = 1,2.  f16 outputs:
// QIh[i][l*32+f] = f16(Q + b1),  RJh[j][l*32+f] = f16(-Q).
// ---------------------------------------------------------------------------
__global__ __launch_bounds__(256) void gud_prep(const float* __restrict__ P,
                                                const float* __restrict__ W1,
                                                const float* __restrict__ b1,
                                                _Float16* __restrict__ QIh,
                                                _Float16* __restrict__ RJh) {
    int gid = blockIdx.x * 256 + threadIdx.x;   // 0 .. NN*64-1
    int i  = gid >> 6;
    int lf = gid & 63;
    int l  = (lf >> 5) + 1;   // 1 or 2
    int f  = lf & 31;
    const float* prow = P + i * FDIM;
    const float* w    = W1 + l * FDIM * FDIM + f;
    float q = 0.f;
#pragma unroll
    for (int c = 0; c < FDIM; ++c) q = fmaf(prow[c], w[c * FDIM], q);
    QIh[i * 64 + lf] = (_Float16)(q + b1[l * FDIM + f]);
    RJh[i * 64 + lf] = (_Float16)(-q);
}

// ---------------------------------------------------------------------------
// Fused MFMA GEMM + conv epilogue, TG=64, 2 blocks/CU.
//   acc = A*A (bf16 hi/lo split), then
//   out[i,j] = A[i,j]*(m1+bb1) + acc[i,j]*(m2+bb2) + (i==j)*c0
// 3 LDS buffers, 2-deep prefetch, counted vmcnt(4) + raw s_barrier.
// Epilogue in f16 (pk_add/pk_max + v_dot2_f32_f16).
// ---------------------------------------------------------------------------
__global__ __launch_bounds__(256, 2) void gud_gemm(
        const unsigned short* __restrict__ Ah,
        const unsigned short* __restrict__ Al,
        const float* __restrict__ A,
        const _Float16* __restrict__ QIh,
        const _Float16* __restrict__ RJh,
        const float* __restrict__ b1,
        const float* __restrict__ W2,
        const float* __restrict__ b2,
        float* __restrict__ out) {
    // 3 gemm bufs (4 subtiles x 64 rows x 64B = 16KB each) + QI(8KB) + RJ(8KB)
    __shared__ char smem[3 * 16384 + 2 * 8192];   // 64 KiB
    char* QIl = smem + 49152;
    char* RJl = smem + 57344;

    const int tid  = threadIdx.x;
    const int lane = tid & 63;
    const int w    = tid >> 6;          // wave 0..3
    const int wr   = w >> 1, wc = w & 1;

    // XCD-chunked swizzle: XCD x gets 3 consecutive i-row panels (576%8==0)
    const int lin = blockIdx.x;
    const int swz = (lin & 7) * 72 + (lin >> 3);
    const int by  = swz / 24;
    const int bx  = swz - by * 24;
    const int i0  = by * TG;
    const int j0  = bx * TG;

    // ---- QI/RJ staging FIRST (oldest in vmcnt FIFO).
    // LDS layout: 16B slot (c*64 + row) = QIh[i0+row][8c..8c+7] (f16).
#pragma unroll
    for (int sl = 0; sl < 2; ++sl) {
        int base = (w * 2 + sl) * 64;       // wave-uniform slot base
        int idx  = base + lane;
        int c    = idx >> 6;
        int row  = idx & 63;
        gload_lds16(QIh + (size_t)(i0 + row) * 64 + c * 8, QIl + base * 16);
    }
#pragma unroll
    for (int sl = 0; sl < 2; ++sl) {
        int base = (w * 2 + sl) * 64;
        int idx  = base + lane;
        int c    = idx >> 6;
        int row  = idx & 63;
        gload_lds16(RJh + (size_t)(j0 + row) * 64 + c * 8, RJl + base * 16);
    }

    // ---- GEMM staging: wave w owns subtile w (0=Ah@i0,1=Al@i0,2=Ah@j0,3=Al@j0)
    const unsigned short* src = (w & 1) ? Al : Ah;
    const int rowbase = (w < 2) ? i0 : j0;
    int goffs[4];
#pragma unroll
    for (int s = 0; s < 4; ++s) {
        int rt    = 16 * s + (lane >> 2);          // row within tile 0..63
        int chunk = (lane & 3) ^ ((rt >> 1) & 3);  // inverse swizzle on source
        goffs[s]  = (rowbase + rt) * (NN * 2) + chunk * 16;
    }

    // ---- fragment read offsets (swizzled)
    int aoff[2], boff[2];
    const int kb = lane >> 4;
#pragma unroll
    for (int m = 0; m < 2; ++m) {
        int ra  = wr * 32 + m * 16 + (lane & 15);
        aoff[m] = ra * 64 + ((kb ^ ((ra >> 1) & 3)) * 16);
        int rb  = wc * 32 + m * 16 + (lane & 15);
        boff[m] = rb * 64 + ((kb ^ ((rb >> 1) & 3)) * 16);
    }

    f32x4 acc[2][2];
#pragma unroll
    for (int m = 0; m < 2; ++m)
#pragma unroll
        for (int n = 0; n < 2; ++n) acc[m][n] = (f32x4){0.f, 0.f, 0.f, 0.f};

    // ---- prologue: stage k-tiles 0,1 into buffers 0,1
#pragma unroll
    for (int s = 0; s < 4; ++s)
        gload_lds16((const char*)src + goffs[s], smem + w * 4096 + s * 1024);
#pragma unroll
    for (int s = 0; s < 4; ++s)
        gload_lds16((const char*)src + goffs[s] + 64, smem + 16384 + w * 4096 + s * 1024);

    auto compute = [&](const char* buf) {
        bf16x8 ahf[2], alf[2], bhf[2], blf[2];
#pragma unroll
        for (int m = 0; m < 2; ++m) {
            ahf[m] = *(const bf16x8*)(buf + 0     + aoff[m]);
            alf[m] = *(const bf16x8*)(buf + 4096  + aoff[m]);
            bhf[m] = *(const bf16x8*)(buf + 8192  + boff[m]);
            blf[m] = *(const bf16x8*)(buf + 12288 + boff[m]);
        }
#pragma unroll
        for (int m = 0; m < 2; ++m)
#pragma unroll
            for (int n = 0; n < 2; ++n) {
                acc[m][n] = __builtin_amdgcn_mfma_f32_16x16x32_bf16(ahf[m], bhf[n], acc[m][n], 0, 0, 0);
                acc[m][n] = __builtin_amdgcn_mfma_f32_16x16x32_bf16(alf[m], bhf[n], acc[m][n], 0, 0, 0);
                acc[m][n] = __builtin_amdgcn_mfma_f32_16x16x32_bf16(ahf[m], blf[n], acc[m][n], 0, 0, 0);
            }
    };

    // ---- main loop: vmcnt(4) retires tile kt (kt+1 stays in flight)
    for (int kt = 0; kt < NT - 1; ++kt) {
        asm volatile("s_waitcnt vmcnt(4)" ::: "memory");
        __builtin_amdgcn_s_barrier();
        if (kt + 2 < NT) {   // stage kt+2 AFTER barrier (its buffer is now free)
            char* dst = smem + ((kt + 2) % 3) * 16384 + w * 4096;
            const int kbyte = (kt + 2) * 64;
#pragma unroll
            for (int s = 0; s < 4; ++s)
                gload_lds16((const char*)src + goffs[s] + kbyte, dst + s * 1024);
        }
        compute(smem + (kt % 3) * 16384);
    }
    asm volatile("s_waitcnt vmcnt(0)" ::: "memory");
    __builtin_amdgcn_s_barrier();
    compute(smem + ((NT - 1) % 3) * 16384);

    // ================= fused conv epilogue (f16) =================
    const int crow = (lane >> 4) * 4;
    const int ccol = lane & 15;
    int il[2], jl[2];
#pragma unroll
    for (int m = 0; m < 2; ++m) il[m] = wr * 32 + m * 16 + crow;
#pragma unroll
    for (int n = 0; n < 2; ++n) jl[n] = wc * 32 + n * 16 + ccol;

    // A values (issued early)
    float av[2][2][4];
#pragma unroll
    for (int m = 0; m < 2; ++m)
#pragma unroll
        for (int n = 0; n < 2; ++n)
#pragma unroll
            for (int r = 0; r < 4; ++r)
                av[m][n][r] = A[(size_t)(i0 + il[m] + r) * NN + j0 + jl[n]];

    float c0 = b2[0];
#pragma unroll
    for (int f = 0; f < FDIM; ++f) c0 = fmaf(fmaxf(b1[f], 0.f), W2[f], c0);
    const float bb1 = b2[1], bb2 = b2[2];

    // W2 (layers 1,2 concatenated: weight for feature f is W2[32+f]) as f16 pairs
    h16x2 w2h[32];
#pragma unroll
    for (int k = 0; k < 32; ++k) {
        h16x2 t; t.x = (_Float16)W2[32 + 2 * k]; t.y = (_Float16)W2[33 + 2 * k];
        w2h[k] = t;
    }

    float m1[2][2][4], m2[2][2][4];
#pragma unroll
    for (int m = 0; m < 2; ++m)
#pragma unroll
        for (int n = 0; n < 2; ++n)
#pragma unroll
            for (int r = 0; r < 4; ++r) { m1[m][n][r] = 0.f; m2[m][n][r] = 0.f; }

#pragma unroll
    for (int c = 0; c < 8; ++c) {              // chunks of 8 f16 features
        uint4 rv[2];
#pragma unroll
        for (int n = 0; n < 2; ++n)
            rv[n] = *(const uint4*)(RJl + (c * 64 + jl[n]) * 16);
        uint4 qv[2][4];
#pragma unroll
        for (int m = 0; m < 2; ++m)
#pragma unroll
            for (int r = 0; r < 4; ++r)
                qv[m][r] = *(const uint4*)(QIl + (c * 64 + il[m] + r) * 16);
#pragma unroll
        for (int m = 0; m < 2; ++m)
#pragma unroll
            for (int n = 0; n < 2; ++n) {
                const unsigned* ru = (const unsigned*)&rv[n];
#pragma unroll
                for (int r = 0; r < 4; ++r) {
                    const unsigned* qu = (const unsigned*)&qv[m][r];
                    float acc_f = (c < 4) ? m1[m][n][r] : m2[m][n][r];
#pragma unroll
                    for (int e = 0; e < 4; ++e) {
                        h16x2 q = __builtin_bit_cast(h16x2, qu[e]);
                        h16x2 j = __builtin_bit_cast(h16x2, ru[e]);
                        h16x2 h = q + j;                       // v_pk_add_f16
                        h16x2 z = {(_Float16)0, (_Float16)0};
                        h = __builtin_elementwise_max(h, z);   // v_pk_max_f16
                        acc_f = __builtin_amdgcn_fdot2(h, w2h[c * 4 + e], acc_f, false);
                    }
                    if (c < 4) m1[m][n][r] = acc_f; else m2[m][n][r] = acc_f;
                }
            }
    }

    // ---- final: out = A*(m1+bb1) + acc*(m2+bb2) + diag(c0)
#pragma unroll
    for (int m = 0; m < 2; ++m)
#pragma unroll
        for (int n = 0; n < 2; ++n)
#pragma unroll
            for (int r = 0; r < 4; ++r) {
                float v = av[m][n][r] * (m1[m][n][r] + bb1)
                        + acc[m][n][r] * (m2[m][n][r] + bb2);
                int gi = i0 + il[m] + r;
                int gj = j0 + jl[n];
                if (gi == gj) v += c0;
                out[(size_t)gi * NN + gj] = v;
            }
}

// ---------------------------------------------------------------------------
extern "C" void kernel_launch(void* const* d_in, const int* in_sizes, int n_in,
                              void* d_out, int out_size, void* d_ws, size_t ws_size,
                              hipStream_t stream) {
    const float* A  = (const float*)d_in[0];   // [NN,NN] A_norm (symmetric)
    const float* P  = (const float*)d_in[1];   // [NN,32]
    const float* W1 = (const float*)d_in[2];   // [3,32,32]
    const float* b1 = (const float*)d_in[3];   // [3,32]
    const float* W2 = (const float*)d_in[4];   // [3,32,1]
    const float* b2 = (const float*)d_in[5];   // [3,1]
    float* out = (float*)d_out;

    unsigned short* Ahh = (unsigned short*)d_ws;                 // NN*NN bf16
    unsigned short* All = Ahh + (size_t)NN * NN;                 // NN*NN bf16
    _Float16* QIh = (_Float16*)(All + (size_t)NN * NN);          // NN*64 f16
    _Float16* RJh = QIh + (size_t)NN * 64;                       // NN*64 f16

    gud_split<<<dim3(NN * NN / 1024), 256, 0, stream>>>(A, Ahh, All);
    gud_prep<<<dim3(NN * 64 / 256), 256, 0, stream>>>(P, W1, b1, QIh, RJh);
    gud_gemm<<<dim3((NN / TG) * (NN / TG)), 256, 0, stream>>>(Ahh, All, A, QIh, RJh,
                                                              b1, W2, b2, out);
}